// Round 4
// baseline (139.145 us; speedup 1.0000x reference)
//
#include <hip/hip_runtime.h>

#define EMB_D 128
#define SLOT_CAP 96   // max stored edges/slot; needed-node mean deg ~21, P(>64) ~ 0

// ---------- Pass 1: claim needed nodes. map[node] = slot+1, slot in [0,2B). ----------
__global__ void claim_kernel(const int* __restrict__ user_idx,
                             const int* __restrict__ item_idx,
                             int* __restrict__ node_map, int B, int U) {
    int t = blockIdx.x * blockDim.x + threadIdx.x;
    if (t >= 2 * B) return;
    int node = (t < B) ? user_idx[t] : (U + item_idx[t - B]);
    atomicCAS(&node_map[node], 0, t + 1);
}

// ---------- Pass 2: bucket filtered edges into per-slot lists, 4 edges/thread. ----------
__device__ __forceinline__ void fill_one(int e, int s,
        const float* __restrict__ user_emb, const float* __restrict__ item_emb,
        const float* __restrict__ vals, const int* __restrict__ cols,
        int* __restrict__ deg, int2* __restrict__ edge_buf,
        float* __restrict__ comp, int U) {
    if (s == 0) return;
    int slot = s - 1;
    int pos = atomicAdd(&deg[slot], 1);
    int c = cols[e];
    float v = vals[e];
    if (pos < SLOT_CAP) {
        edge_buf[(size_t)slot * SLOT_CAP + pos] = make_int2(c, __float_as_int(v));
    } else {  // ~never: exact fallback, comp pre-zeroed
        const float* src = (c < U) ? (user_emb + (size_t)c * EMB_D)
                                   : (item_emb + (size_t)(c - U) * EMB_D);
        float* dst = comp + (size_t)slot * EMB_D;
        for (int i = 0; i < EMB_D; ++i) atomicAdd(dst + i, v * src[i]);
    }
}

__global__ void fill_kernel(const float* __restrict__ user_emb,
                            const float* __restrict__ item_emb,
                            const float* __restrict__ vals,
                            const int* __restrict__ rows,
                            const int* __restrict__ cols,
                            const int* __restrict__ node_map,
                            int* __restrict__ deg,
                            int2* __restrict__ edge_buf,
                            float* __restrict__ comp,
                            int nnz, int U) {
    int t = blockIdx.x * blockDim.x + threadIdx.x;
    int e = t * 4;
    if (e >= nnz) return;
    if (e + 3 < nnz) {
        int4 r4 = *(const int4*)(rows + e);
        int s0 = node_map[r4.x];          // 4 independent lookups in flight
        int s1 = node_map[r4.y];
        int s2 = node_map[r4.z];
        int s3 = node_map[r4.w];
        fill_one(e,     s0, user_emb, item_emb, vals, cols, deg, edge_buf, comp, U);
        fill_one(e + 1, s1, user_emb, item_emb, vals, cols, deg, edge_buf, comp, U);
        fill_one(e + 2, s2, user_emb, item_emb, vals, cols, deg, edge_buf, comp, U);
        fill_one(e + 3, s3, user_emb, item_emb, vals, cols, deg, edge_buf, comp, U);
    } else {
        for (int k = e; k < nnz; ++k)
            fill_one(k, node_map[rows[k]], user_emb, item_emb, vals, cols,
                     deg, edge_buf, comp, U);
    }
}

// ---------- Pass 3: one wave per slot; edge list pre-loaded per-lane, shfl ----------
// broadcast (no memory dependence), 8 row-gathers in flight, register accumulate.
__global__ void gather_kernel(const float* __restrict__ user_emb,
                              const float* __restrict__ item_emb,
                              const int2* __restrict__ edge_buf,
                              const int* __restrict__ deg,
                              float* __restrict__ comp,
                              int nslots, int U) {
    int wid  = (blockIdx.x * blockDim.x + threadIdx.x) >> 6;
    int lane = threadIdx.x & 63;
    if (wid >= nslots) return;
    int d = deg[wid];
    bool ovf = (d > SLOT_CAP);
    int dc = ovf ? SLOT_CAP : d;
    const int2* eb = edge_buf + (size_t)wid * SLOT_CAP;
    float* dst = comp + (size_t)wid * EMB_D + lane * 2;

    // One coalesced 512B load: lane i owns edge i (valid only for lane < dc;
    // garbage lanes are never used as shfl sources and never dereference).
    int2 my_e = eb[lane];                      // in-bounds: SLOT_CAP >= 64
    int  myc  = my_e.x;
    const float* mybase = (myc < U) ? (user_emb + (size_t)myc * EMB_D)
                                    : (item_emb + (size_t)(myc - U) * EMB_D);
    unsigned long long mba = (unsigned long long)mybase;
    int   b_lo = (int)(unsigned)mba;
    int   b_hi = (int)(mba >> 32);
    float myv  = __int_as_float(my_e.y);

    float2 a[8];
#pragma unroll
    for (int k = 0; k < 8; ++k) a[k] = make_float2(0.f, 0.f);

    int n0 = dc < 64 ? dc : 64;
    for (int j = 0; j < n0; j += 8) {
        const float* p[8];
        float vv[8];
#pragma unroll
        for (int k = 0; k < 8; ++k) {
            int jj = (j + k < n0) ? (j + k) : (n0 - 1);   // wave-uniform
            int   lo = __shfl(b_lo, jj);
            int   hi = __shfl(b_hi, jj);
            float v  = __shfl(myv, jj);
            vv[k] = (j + k < n0) ? v : 0.f;               // mask tail
            p[k]  = (const float*)(((unsigned long long)(unsigned)hi << 32)
                                   | (unsigned)lo);
        }
        float2 x[8];
#pragma unroll
        for (int k = 0; k < 8; ++k) x[k] = *(const float2*)(p[k] + lane * 2);
#pragma unroll
        for (int k = 0; k < 8; ++k) {
            a[k].x = fmaf(vv[k], x[k].x, a[k].x);
            a[k].y = fmaf(vv[k], x[k].y, a[k].y);
        }
    }

    // rare: degree in (64, SLOT_CAP] -> per-edge broadcast loads
    float2 tl = make_float2(0.f, 0.f);
    for (int j = 64; j < dc; ++j) {
        int2 ed = eb[j];
        int c = ed.x;
        float v = __int_as_float(ed.y);
        const float* src = (c < U) ? (user_emb + (size_t)c * EMB_D)
                                   : (item_emb + (size_t)(c - U) * EMB_D);
        float2 x = *(const float2*)(src + lane * 2);
        tl.x = fmaf(v, x.x, tl.x);
        tl.y = fmaf(v, x.y, tl.y);
    }

    float rx = ((a[0].x + a[1].x) + (a[2].x + a[3].x))
             + ((a[4].x + a[5].x) + (a[6].x + a[7].x)) + tl.x;
    float ry = ((a[0].y + a[1].y) + (a[2].y + a[3].y))
             + ((a[4].y + a[5].y) + (a[6].y + a[7].y)) + tl.y;
    if (ovf) { dst[0] += rx; dst[1] += ry; }  // overflow part already added atomically
    else     { dst[0] = rx;  dst[1] = ry; }   // includes d==0 -> store zeros
}

// ---------- Pass 4: per-pair fused gather + dot. One wave per output. ----------
__global__ void final_kernel(const float* __restrict__ user_emb,
                             const float* __restrict__ item_emb,
                             const int* __restrict__ user_idx,
                             const int* __restrict__ item_idx,
                             const int* __restrict__ node_map,
                             const float* __restrict__ comp,
                             float* __restrict__ out, int B, int U) {
    int wid  = (blockIdx.x * blockDim.x + threadIdx.x) >> 6;
    int lane = threadIdx.x & 63;
    if (wid >= B) return;
    int un  = user_idx[wid];
    int inn = item_idx[wid];
    int su  = node_map[un] - 1;
    int si  = node_map[U + inn] - 1;
    float2 eu = *(const float2*)(user_emb + (size_t)un * EMB_D + lane * 2);
    float2 ei = *(const float2*)(item_emb + (size_t)inn * EMB_D + lane * 2);
    float2 cu = *(const float2*)(comp + (size_t)su * EMB_D + lane * 2);
    float2 ci = *(const float2*)(comp + (size_t)si * EMB_D + lane * 2);
    float p = (eu.x + cu.x) * (ei.x + ci.x) + (eu.y + cu.y) * (ei.y + ci.y);
#pragma unroll
    for (int off = 32; off; off >>= 1) p += __shfl_down(p, off);
    if (lane == 0) out[wid] = 0.25f * p;
}

// ---------- Fallback (ws too small): direct atomic scatter ----------
__global__ void scatter_kernel(const float* __restrict__ user_emb,
                               const float* __restrict__ item_emb,
                               const float* __restrict__ vals,
                               const int* __restrict__ rows,
                               const int* __restrict__ cols,
                               const int* __restrict__ node_map,
                               float* __restrict__ comp,
                               int nnz, int U) {
    int e = blockIdx.x * blockDim.x + threadIdx.x;
    int lane = threadIdx.x & 63;
    int s = 0; int c = 0; float v = 0.f;
    if (e < nnz) {
        int r = rows[e];
        s = node_map[r];
        if (s != 0) { c = cols[e]; v = vals[e]; }
    }
    unsigned long long mask = __ballot(s != 0);
    while (mask) {
        int j = __ffsll(mask) - 1;
        mask &= mask - 1;
        int   cj    = __shfl(c, j);
        float vj    = __shfl(v, j);
        int   slotj = __shfl(s, j) - 1;
        const float* src = (cj < U) ? (user_emb + (size_t)cj * EMB_D)
                                    : (item_emb + (size_t)(cj - U) * EMB_D);
        float2 x = *(const float2*)(src + lane * 2);
        float* dst = comp + (size_t)slotj * EMB_D + lane * 2;
        atomicAdd(dst,     x.x * vj);
        atomicAdd(dst + 1, x.y * vj);
    }
}

extern "C" void kernel_launch(void* const* d_in, const int* in_sizes, int n_in,
                              void* d_out, int out_size, void* d_ws, size_t ws_size,
                              hipStream_t stream) {
    const float* user_emb = (const float*)d_in[0];
    const float* item_emb = (const float*)d_in[1];
    const float* adj_vals = (const float*)d_in[2];
    const int*   adj_rows = (const int*)d_in[3];
    const int*   adj_cols = (const int*)d_in[4];
    const int*   user_idx = (const int*)d_in[5];
    const int*   item_idx = (const int*)d_in[6];
    float* out = (float*)d_out;

    int U   = in_sizes[0] / EMB_D;
    int I   = in_sizes[1] / EMB_D;
    int N   = U + I;
    int nnz = in_sizes[2];
    int B   = in_sizes[5];
    int S   = 2 * B;                       // slot count

    // Workspace layout: [comp S*D f32][node_map N i32][deg S i32][edge_buf S*CAP int2]
    size_t comp_bytes = (size_t)S * EMB_D * sizeof(float);
    size_t map_bytes  = ((size_t)N * sizeof(int) + 15) & ~(size_t)15;
    size_t deg_bytes  = (size_t)S * sizeof(int);
    size_t edge_bytes = (size_t)S * SLOT_CAP * sizeof(int2);

    float* comp     = (float*)d_ws;
    int*   node_map = (int*)((char*)d_ws + comp_bytes);
    int*   deg      = (int*)((char*)d_ws + comp_bytes + map_bytes);
    int2*  edge_buf = (int2*)((char*)d_ws + comp_bytes + map_bytes + deg_bytes);

    if (ws_size >= comp_bytes + map_bytes + deg_bytes + edge_bytes) {
        // comp must be zero for the (theoretical) overflow atomic path in fill.
        hipMemsetAsync(d_ws, 0, comp_bytes + map_bytes + deg_bytes, stream);
        claim_kernel<<<(S + 255) / 256, 256, 0, stream>>>(user_idx, item_idx,
                                                          node_map, B, U);
        int fill_threads = (nnz + 3) / 4;
        fill_kernel<<<(fill_threads + 255) / 256, 256, 0, stream>>>(
            user_emb, item_emb, adj_vals, adj_rows, adj_cols, node_map,
            deg, edge_buf, comp, nnz, U);
        gather_kernel<<<(S * 64 + 255) / 256, 256, 0, stream>>>(user_emb, item_emb,
                                                                edge_buf, deg, comp,
                                                                S, U);
    } else {
        hipMemsetAsync(d_ws, 0, comp_bytes + map_bytes, stream);
        claim_kernel<<<(S + 255) / 256, 256, 0, stream>>>(user_idx, item_idx,
                                                          node_map, B, U);
        scatter_kernel<<<(nnz + 255) / 256, 256, 0, stream>>>(user_emb, item_emb,
                                                              adj_vals, adj_rows,
                                                              adj_cols, node_map,
                                                              comp, nnz, U);
    }
    final_kernel<<<(B * 64 + 255) / 256, 256, 0, stream>>>(user_emb, item_emb,
                                                           user_idx, item_idx,
                                                           node_map, comp, out,
                                                           B, U);
}